// Round 6
// baseline (146.729 us; speedup 1.0000x reference)
//
#include <hip/hip_runtime.h>
#include <hip/hip_cooperative_groups.h>

#define BB 16
#define SS 2048
#define DD 64
#define OO 128
#define SPL 16
#define YN (BB * OO * DD)   // 131072 Y elements

typedef __attribute__((ext_vector_type(8))) short short8;   // 8 bf16 = 4 VGPRs
typedef __attribute__((ext_vector_type(4))) float f32x4;

__device__ __forceinline__ unsigned short f2bf(float f) {   // RNE fp32->bf16
    unsigned int u = __float_as_uint(f);
    return (unsigned short)((u + 0x7FFF + ((u >> 16) & 1)) >> 16);
}
__device__ __forceinline__ unsigned int pk2(float x, float y) {
    return (unsigned int)f2bf(x) | ((unsigned int)f2bf(y) << 16);
}
__device__ __forceinline__ short8 cvt8(float4 a, float4 b) {
    uint4 u = make_uint4(pk2(a.x, a.y), pk2(a.z, a.w), pk2(b.x, b.y), pk2(b.z, b.w));
    return *(short8*)&u;
}

// ---------------------------------------------------------------------------
// One cooperative kernel, 256 blocks x 512 thr (1 block/CU, 8 waves, 17KB LDS
// -> co-residency guaranteed). Three phases over two grid.sync():
// P1 (== R5 k_yf): Yp[p][b][o][d] fp32 = sum_{t in 128-slice} W[o,t]*X[b,t,d]
//     via bf16 MFMA; X slice transposed to bf16 in LDS (stride 132), W
//     fragments inline-converted from global fp32 (L2-shared by 16 b-blocks).
// P2: Y = sum_p Yp, emitted as bf16 YB in the XOR-swizzled layout P3 reads:
//     elem(b,o,c) -> (b*128+o)*64 + (((c>>3)^(o&7))<<3 | (c&7)).
//     1 element/thread, 131072 threads == YN, coalesced slab reads.
// P3 (== R5 k_outf, s-tile 128): out[b,s,o] = sum_d X*Y + bias; A-frags
//     inline-cvt from X fp32, B-frags 16B global loads from swizzled YB
//     (L2 broadcast), direct fp32 stores.
// ---------------------------------------------------------------------------
__global__ __launch_bounds__(512) void k_all(const float* __restrict__ X,
                                             const float* __restrict__ W,
                                             const float* __restrict__ bias,
                                             float* __restrict__ out,
                                             float* __restrict__ Yp,
                                             unsigned short* __restrict__ YB) {
    cooperative_groups::grid_group grid = cooperative_groups::this_grid();
    __shared__ unsigned short XT[64 * 132];

    const int bx  = blockIdx.x;
    const int tid = threadIdx.x;
    const int w   = tid >> 6;
    const int l   = tid & 63;
    const int n   = l & 15;
    const int q   = l >> 4;

    // ---------------- P1: split-K partial GEMM ----------------
    {
        const int b  = bx & 15;
        const int p  = bx >> 4;
        const int t0 = p * (SS / SPL);     // 128-wide t slice

        const float* Xb = X + ((size_t)b * SS + t0) * DD;
#pragma unroll
        for (int i = 0; i < 4; ++i) {
            const int tl = w * 4 + i * 32;                 // 0..124 step 4
            float x0 = Xb[(size_t)(tl + 0) * DD + l];
            float x1 = Xb[(size_t)(tl + 1) * DD + l];
            float x2 = Xb[(size_t)(tl + 2) * DD + l];
            float x3 = Xb[(size_t)(tl + 3) * DD + l];
            *(uint2*)&XT[l * 132 + tl] = make_uint2(pk2(x0, x1), pk2(x2, x3));
        }
        __syncthreads();

        f32x4 acc[4];
#pragma unroll
        for (int j = 0; j < 4; ++j) acc[j] = {0.f, 0.f, 0.f, 0.f};

        const float* Wr = W + (size_t)(w * 16 + n) * SS + t0;
#pragma unroll
        for (int kk = 0; kk < SS / SPL; kk += 32) {
            const float4 wa = *(const float4*)(Wr + kk + q * 8);
            const float4 wb = *(const float4*)(Wr + kk + q * 8 + 4);
            const short8 a  = cvt8(wa, wb);
#pragma unroll
            for (int j = 0; j < 4; ++j) {
                const unsigned short* r = &XT[(j * 16 + n) * 132 + kk + q * 8];
                uint2 lo = *(const uint2*)(r);
                uint2 hi = *(const uint2*)(r + 4);
                uint4 u  = make_uint4(lo.x, lo.y, hi.x, hi.y);
                acc[j] = __builtin_amdgcn_mfma_f32_16x16x32_bf16(a, *(short8*)&u, acc[j], 0, 0, 0);
            }
        }

        float* Yb = Yp + ((size_t)(p * BB + b) * OO + w * 16 + q * 4) * DD;
#pragma unroll
        for (int j = 0; j < 4; ++j)
#pragma unroll
            for (int r = 0; r < 4; ++r)
                Yb[(size_t)r * DD + j * 16 + n] = acc[j][r];
    }
    grid.sync();

    // ---------------- P2: reduce 16 slabs -> swizzled bf16 YB ----------------
    {
        const int g = bx * 512 + tid;      // 0..YN-1
        float a = Yp[g];
#pragma unroll
        for (int p = 1; p < SPL; ++p) a += Yp[(size_t)p * YN + g];
        const int c = g & 63;
        const int o = (g >> 6) & (OO - 1);
        const int b = g >> 13;
        const int e = ((b * OO + o) << 6) + ((((c >> 3) ^ (o & 7)) << 3) | (c & 7));
        YB[e] = f2bf(a);
    }
    grid.sync();

    // ---------------- P3: out = X @ Y^T + bias ----------------
    {
        const int b  = bx >> 4;
        const int s0 = (bx & 15) * 128;

        float bv[8];
#pragma unroll
        for (int j = 0; j < 8; ++j) bv[j] = bias[j * 16 + n];

        f32x4 acc[8];
#pragma unroll
        for (int j = 0; j < 8; ++j) acc[j] = {0.f, 0.f, 0.f, 0.f};

        const float*          Xr  = X  + ((size_t)b * SS + s0 + w * 16 + n) * DD;
        const unsigned short* Yb2 = YB + (size_t)b * OO * DD;

#pragma unroll
        for (int kk = 0; kk < DD; kk += 32) {
            const float4 xa = *(const float4*)(Xr + kk + q * 8);
            const float4 xb = *(const float4*)(Xr + kk + q * 8 + 4);
            const short8 a  = cvt8(xa, xb);
            const int c8    = (kk >> 3) + q;
#pragma unroll
            for (int j = 0; j < 8; ++j) {
                const int o = j * 16 + n;
                const uint4 u = *(const uint4*)(Yb2 + o * 64 + ((c8 ^ (o & 7)) << 3));
                acc[j] = __builtin_amdgcn_mfma_f32_16x16x32_bf16(a, *(short8*)&u, acc[j], 0, 0, 0);
            }
        }

        float* op = out + ((size_t)b * SS + s0 + w * 16 + q * 4) * OO;
#pragma unroll
        for (int j = 0; j < 8; ++j)
#pragma unroll
            for (int r = 0; r < 4; ++r)
                op[(size_t)r * OO + j * 16 + n] = acc[j][r] + bv[j];
    }
}

extern "C" void kernel_launch(void* const* d_in, const int* in_sizes, int n_in,
                              void* d_out, int out_size, void* d_ws, size_t ws_size,
                              hipStream_t stream) {
    const float* X    = (const float*)d_in[0];  // [B,S,D]
    const float* W    = (const float*)d_in[1];  // [OUT,S]
    const float* bias = (const float*)d_in[2];  // [OUT]
    float* out = (float*)d_out;                 // [B,S,OUT]

    float*          Yp = (float*)d_ws;                       // [SPL][B][OO][DD] fp32, 8.4MB
    unsigned short* YB = (unsigned short*)(Yp + (size_t)SPL * YN);  // swizzled bf16, 256KB

    void* args[] = {(void*)&X, (void*)&W, (void*)&bias, (void*)&out,
                    (void*)&Yp, (void*)&YB};
    hipLaunchCooperativeKernel((const void*)k_all, dim3(256), dim3(512),
                               args, 0, stream);
}

// Round 7
// 96.357 us; speedup vs baseline: 1.5228x; 1.5228x over previous
//
#include <hip/hip_runtime.h>

#define BB 16
#define SS 2048
#define DD 64
#define OO 128
#define XTS 260   // XT row stride in elems: 256 t + 4 pad; rows 8B-aligned

typedef __attribute__((ext_vector_type(8))) short short8;   // 8 bf16 = 4 VGPRs
typedef __attribute__((ext_vector_type(4))) float f32x4;

__device__ __forceinline__ unsigned short f2bf(float f) {   // RNE fp32->bf16
    unsigned int u = __float_as_uint(f);
    return (unsigned short)((u + 0x7FFF + ((u >> 16) & 1)) >> 16);
}
__device__ __forceinline__ unsigned int pk2(float x, float y) {
    return (unsigned int)f2bf(x) | ((unsigned int)f2bf(y) << 16);
}
__device__ __forceinline__ short8 cvt8(float4 a, float4 b) {
    uint4 u = make_uint4(pk2(a.x, a.y), pk2(a.z, a.w), pk2(b.x, b.y), pk2(b.z, b.w));
    return *(short8*)&u;
}

// ---------------------------------------------------------------------------
// ONE plain dispatch. grid = 256 blocks x 512 thr (1 block/CU, 8 waves).
// block = (b = bx&15, ot = (bx>>4)&7, sh = bx>>7):
//   P1: recompute Y-slice [16 o][64 d] = sum_{t<2048} W[ot*16+o, t] * X[b,t,d]
//       (4.2 MFLOP/block -> 1.07 GFLOP chip-wide; the o-tile split makes
//        per-block recompute cheap, so no cross-block dependency exists).
//       K staged as 8 x 256-t chunks, ping-pong LDS, transposed to bf16
//       (R5 k_yf staging pattern). Wave w: d-tile j=w&3, t-half h=w>>2;
//       8 partials reduced via LDS -> YL bf16, R5's XOR swizzle.
//   P3: out[b, s-half, ot*16..+16] = X @ Yslice^T + bias (R5 k_outf math:
//       A inline-cvt from fp32 X, B = 16B uint4 from YL, direct stores).
// No workspace, no atomics, no inter-block communication.
// ---------------------------------------------------------------------------
__global__ __launch_bounds__(512) void k_fused(const float* __restrict__ X,
                                               const float* __restrict__ W,
                                               const float* __restrict__ bias,
                                               float* __restrict__ out) {
    __shared__ unsigned short XT[2][64 * XTS];  // ping-pong [d][t-chunk] bf16
    __shared__ float Yred[8][16][16];           // per-wave partials
    __shared__ unsigned short YL[16 * 64];      // Y-slice bf16, swizzled

    const int bx  = blockIdx.x;
    const int b   = bx & 15;          // low bits: blocks sharing X[b] cluster per XCD
    const int ot  = (bx >> 4) & 7;
    const int sh  = bx >> 7;
    const int tid = threadIdx.x;
    const int w   = tid >> 6;
    const int l   = tid & 63;
    const int n   = l & 15;
    const int q   = l >> 4;

    const float* Xb = X + (size_t)b * SS * DD;

    // ---------------- P1: Y-slice recompute ----------------
    const int j = w & 3;    // d-tile: d in [j*16, j*16+16)
    const int h = w >> 2;   // t-half within each 256-chunk
    const float* Wr = W + (size_t)(ot * 16 + n) * SS;

    f32x4 acc = {0.f, 0.f, 0.f, 0.f};
    for (int c = 0; c < 8; ++c) {
        unsigned short* xt = XT[c & 1];
        const int t0 = c * 256;
        // stage: lane l = d; 4-t groups, coalesced 256B row loads, uint2 LDS writes
#pragma unroll
        for (int i = 0; i < 8; ++i) {
            const int tl = w * 4 + i * 32;            // 0..252 step 4 per wave
            const float x0 = Xb[(size_t)(t0 + tl + 0) * DD + l];
            const float x1 = Xb[(size_t)(t0 + tl + 1) * DD + l];
            const float x2 = Xb[(size_t)(t0 + tl + 2) * DD + l];
            const float x3 = Xb[(size_t)(t0 + tl + 3) * DD + l];
            *(uint2*)&xt[l * XTS + tl] = make_uint2(pk2(x0, x1), pk2(x2, x3));
        }
        __syncthreads();   // one barrier/chunk is safe with ping-pong buffers

        const unsigned short* xr = &xt[(j * 16 + n) * XTS + h * 128];
        const float*          wp = Wr + t0 + h * 128;
#pragma unroll
        for (int kk = 0; kk < 128; kk += 32) {
            const float4 wa = *(const float4*)(wp + kk + q * 8);
            const float4 wb = *(const float4*)(wp + kk + q * 8 + 4);
            const short8 a  = cvt8(wa, wb);
            const uint2 lo  = *(const uint2*)(xr + kk + q * 8);
            const uint2 hi  = *(const uint2*)(xr + kk + q * 8 + 4);
            uint4 u = make_uint4(lo.x, lo.y, hi.x, hi.y);
            acc = __builtin_amdgcn_mfma_f32_16x16x32_bf16(a, *(short8*)&u, acc, 0, 0, 0);
        }
    }

    // partials: D elem (o-row = q*4+r, d-col = j*16+n)
#pragma unroll
    for (int r = 0; r < 4; ++r)
        Yred[w][q * 4 + r][n] = acc[r];
    __syncthreads();

    // reduce pairs (h=0 at w=j, h=1 at w=j+4) -> YL bf16 swizzled
#pragma unroll
    for (int e = tid; e < 16 * 64; e += 512) {
        const int o  = e >> 6;
        const int d  = e & 63;
        const int jj = d >> 4;
        const int dd = d & 15;
        const float v = Yred[jj][o][dd] + Yred[jj + 4][o][dd];
        const int c8  = d >> 3;
        YL[o * 64 + ((((c8) ^ (o & 7)) << 3) | (d & 7))] = f2bf(v);
    }
    __syncthreads();

    // ---------------- P3: out tile ----------------
    const float bv   = bias[ot * 16 + n];
    const int sbase  = sh * 1024 + w * 128;

    // hoist B-frags (K=64 -> 2 kk steps), conflict-engineered uint4 reads
    uint4 bf[2];
#pragma unroll
    for (int k2 = 0; k2 < 2; ++k2) {
        const int c8 = k2 * 4 + q;
        bf[k2] = *(const uint4*)&YL[n * 64 + ((c8 ^ (n & 7)) << 3)];
    }

#pragma unroll
    for (int mt = 0; mt < 8; ++mt) {
        const float* Xr = Xb + (size_t)(sbase + mt * 16 + n) * DD;
        f32x4 o4 = {0.f, 0.f, 0.f, 0.f};
#pragma unroll
        for (int k2 = 0; k2 < 2; ++k2) {
            const float4 xa = *(const float4*)(Xr + k2 * 32 + q * 8);
            const float4 xb = *(const float4*)(Xr + k2 * 32 + q * 8 + 4);
            o4 = __builtin_amdgcn_mfma_f32_16x16x32_bf16(cvt8(xa, xb),
                                                         *(short8*)&bf[k2], o4, 0, 0, 0);
        }
        float* op = out + ((size_t)b * SS + sbase + mt * 16 + q * 4) * OO + ot * 16 + n;
#pragma unroll
        for (int r = 0; r < 4; ++r)
            op[(size_t)r * OO] = o4[r] + bv;
    }
}

extern "C" void kernel_launch(void* const* d_in, const int* in_sizes, int n_in,
                              void* d_out, int out_size, void* d_ws, size_t ws_size,
                              hipStream_t stream) {
    const float* X    = (const float*)d_in[0];  // [B,S,D]
    const float* W    = (const float*)d_in[1];  // [OUT,S]
    const float* bias = (const float*)d_in[2];  // [OUT]
    float* out = (float*)d_out;                 // [B,S,OUT]

    k_fused<<<dim3(256), dim3(512), 0, stream>>>(X, W, bias, out);
}